// Round 20
// baseline (265.031 us; speedup 1.0000x reference)
//
#include <hip/hip_runtime.h>

// ---------------------------------------------------------------------------
// TransformerBlock on MI355X (gfx950): bf16 MFMA pipeline
//   B=4 S=2048 D=768 H=12 hs=64 F=3072, M=B*S=8192
// Round 20: R19 base (258.4 us best) + W1 moved to gemm_skb as well
//           (in-block split-K, 12 steps/pipeline, relu bit added to skb
//           epilogue). All four GEMMs now on the split-K structure.
// ---------------------------------------------------------------------------

typedef __attribute__((ext_vector_type(4))) float f32x4;
typedef __attribute__((ext_vector_type(8))) short bf16x8;   // 8 bf16 in 4 VGPRs
typedef __attribute__((ext_vector_type(4))) unsigned short u16x4;

#define GLB_AS __attribute__((address_space(1)))
#define LDS_AS __attribute__((address_space(3)))

__device__ __forceinline__ unsigned short f2bf(float f) {
  unsigned int u = __float_as_uint(f);
  u = (u + 0x7FFFu + ((u >> 16) & 1u)) >> 16;   // RNE
  return (unsigned short)u;
}

__device__ __forceinline__ void gload16(const void* g, void* l) {
  __builtin_amdgcn_global_load_lds((const GLB_AS unsigned int*)g,
                                   (LDS_AS unsigned int*)l, 16, 0, 0);
}

// bijective XCD swizzle (m204): contiguous chunk of wg-ids per XCD
__device__ __forceinline__ int xcd_swz(int orig, int nwg) {
  int q = nwg >> 3, r = nwg & 7;
  int xcd = orig & 7, rest = orig >> 3;
  return (xcd < r ? xcd * (q + 1) : r * (q + 1) + (xcd - r) * q) + rest;
}

#define VMW4 asm volatile("s_waitcnt vmcnt(4)" ::: "memory")
#define VMW0 asm volatile("s_waitcnt vmcnt(0)" ::: "memory")

// ----------------------------------------------- fused prep (one launch) ---
// blocks [0,6144): castx | [6144,7872): Wq/Wk/Wv transpose | [7872,13056): W
__global__ void prep(const float* __restrict__ x, unsigned short* __restrict__ xb,
                     const float* __restrict__ Wq, const float* __restrict__ Wk,
                     const float* __restrict__ Wv, unsigned short* __restrict__ wqkvT,
                     const float* __restrict__ Wo, const float* __restrict__ W1,
                     const float* __restrict__ W2, unsigned short* __restrict__ woT,
                     unsigned short* __restrict__ w1T, unsigned short* __restrict__ w2T,
                     float qscale) {
  __shared__ float tile[32][33];
  const int id = blockIdx.x;
  const int tid = threadIdx.x;

  if (id < 6144) {                       // ---- castx: 6144*256*4 = 6291456
    int i = (id * 256 + tid) * 4;
    float4 f = *(const float4*)&x[i];
    u16x4 o;
    o[0] = f2bf(f.x); o[1] = f2bf(f.y); o[2] = f2bf(f.z); o[3] = f2bf(f.w);
    *(u16x4*)&xb[i] = o;
    return;
  }

  const int tx = tid & 31, ty = tid >> 5;     // (32,8) mapping
  const float* in; unsigned short* out; int C, R, bx, by; float scale = 1.0f;

  if (id < 7872) {                       // ---- tcast3: Wq/Wk/Wv [768x64] x36
    int id2 = id - 6144;                 // [0,1728)
    int z = id2 / 48, rem = id2 % 48;
    int wsel = z / 12, head = z % 12;
    R = 768; C = 64;
    in = (wsel == 0 ? Wq : wsel == 1 ? Wk : Wv) + (size_t)head * R * C;
    out = wqkvT + (size_t)wsel * R * R + (size_t)head * R * C;
    if (wsel == 0) scale = qscale;
    bx = (rem & 1) * 32; by = (rem >> 1) * 32;
  } else {                               // ---- tcastW: Wo/W1/W2
    int id3 = id - 7872;                 // [0,5184)
    int gx;
    if (id3 < 576)       {             in = Wo; out = woT; C = 768;  gx = 24; R = 768; }
    else if (id3 < 2880) { id3 -= 576;  in = W1; out = w1T; C = 3072; gx = 96; R = 768; }
    else                 { id3 -= 2880; in = W2; out = w2T; C = 768;  gx = 24; R = 3072; }
    bx = (id3 % gx) * 32; by = (id3 / gx) * 32;
  }

  #pragma unroll
  for (int i = 0; i < 32; i += 8)
    tile[ty + i][tx] = in[(size_t)(by + ty + i) * C + bx + tx];
  __syncthreads();
  #pragma unroll
  for (int i = 0; i < 32; i += 8)
    out[(size_t)(bx + ty + i) * R + by + tx] = f2bf(tile[tx][ty + i] * scale);
}

// ------------------------------------------------- v -> vT (bf16->bf16) ----
__global__ void vtrans(const unsigned short* __restrict__ v, unsigned short* __restrict__ vT) {
  __shared__ unsigned short tile[32][33];
  int bh = blockIdx.z, b = bh / 12, h = bh % 12;
  int s0 = blockIdx.x * 32, e0 = blockIdx.y * 32;
  int tx = threadIdx.x, ty = threadIdx.y;
  #pragma unroll
  for (int i = 0; i < 32; i += 8)
    tile[ty + i][tx] = v[(size_t)(b * 2048 + s0 + ty + i) * 768 + h * 64 + e0 + tx];
  __syncthreads();
  #pragma unroll
  for (int i = 0; i < 32; i += 8)
    vT[(size_t)((b * 12 + h) * 64 + e0 + ty + i) * 2048 + s0 + tx] = tile[tx][ty + i];
}

// --------------------------------------- GEMM 128x128, in-block split-K ---
// (QKV / Wo / W1 / W2) 8 waves = 2 pipelines x 4 waves; pipeline p covers
// K-half p in its own 32KB LDS double-buffer (64KB total, 2 blocks/CU).
// Combine: pipeline1 acc -> LDS, __syncthreads, pipeline0 adds + epilogue.
// EPI bits: 1 bias, 2 relu, 4 resid(fp32), 8 fp32 store, 16 bf16 store,
//           32 QKV split bf16 store (row stride 768, seg stride segN).
template <int EPI>
__global__ __launch_bounds__(512, 2)
void gemm_skb(const unsigned short* __restrict__ A,
              const unsigned short* __restrict__ Bt,
              const float* __restrict__ bias,
              const float* __restrict__ resid,
              float* __restrict__ Cf,
              unsigned short* __restrict__ Cb,
              int M, int N, int K, int gy, size_t segN) {
  __shared__ unsigned short SH[32768];          // 64 KB
  const int tid = threadIdx.x;
  const int lane = tid & 63;
  const int w = tid >> 6;
  const int pk = w >> 2;                        // pipeline 0/1
  const int wl = w & 3;
  const int wm = wl & 1, wn = wl >> 1;

  const int wg = xcd_swz(blockIdx.x, gridDim.x);
  const int gsz = 8 * gy;
  const int group = wg / gsz;
  const int rem = wg - group * gsz;
  const int bm = (group * 8 + (rem & 7)) * 128;
  const int bn = (rem >> 3) * 128;

  const int Kh = K >> 1;
  const int kof = pk * Kh;
  unsigned short* Abase = SH + pk * 8192;           // [buf][128*32]
  unsigned short* Bbase = SH + 16384 + pk * 8192;

  f32x4 acc[4][4] = {};

  const int st = tid & 255;                     // per-pipeline staging id
  const int r0 = st >> 2;
  const int c0 = (st & 3) * 8;

  // prologue: stage K-half tile 0 into buf 0 (each pipeline its own)
  #pragma unroll
  for (int i = 0; i < 2; ++i) {
    int row = r0 + i * 64;
    gload16(&A[(size_t)(bm + row) * K + kof + c0], &Abase[row * 32 + c0]);
    gload16(&Bt[(size_t)(bn + row) * K + kof + c0], &Bbase[row * 32 + c0]);
  }
  __syncthreads();

  int buf = 0;
  for (int k0 = 0; k0 < Kh; k0 += 32) {
    if (k0 + 32 < Kh) {
      #pragma unroll
      for (int i = 0; i < 2; ++i) {
        int row = r0 + i * 64;
        gload16(&A[(size_t)(bm + row) * K + kof + k0 + 32 + c0],
                &Abase[(buf ^ 1) * 4096 + row * 32 + c0]);
        gload16(&Bt[(size_t)(bn + row) * K + kof + k0 + 32 + c0],
                &Bbase[(buf ^ 1) * 4096 + row * 32 + c0]);
      }
      VMW4;
    } else {
      VMW0;
    }
    __builtin_amdgcn_s_barrier();

    bf16x8 af[4], bf[4];
    #pragma unroll
    for (int m = 0; m < 4; ++m)
      af[m] = *(const bf16x8*)&Abase[buf * 4096 + (wm * 64 + m * 16 + (lane & 15)) * 32 + (lane >> 4) * 8];
    #pragma unroll
    for (int n = 0; n < 4; ++n)
      bf[n] = *(const bf16x8*)&Bbase[buf * 4096 + (wn * 64 + n * 16 + (lane & 15)) * 32 + (lane >> 4) * 8];
    #pragma unroll
    for (int m = 0; m < 4; ++m)
      #pragma unroll
      for (int n = 0; n < 4; ++n)
        acc[m][n] = __builtin_amdgcn_mfma_f32_16x16x32_bf16(af[m], bf[n], acc[m][n], 0, 0, 0);

    __builtin_amdgcn_s_barrier();
    buf ^= 1;
  }

  // combine the two K-half partials via LDS (full compiler fence both sides)
  __syncthreads();
  float* ex = (float*)SH;                       // 16384 floats = 64 KB
  if (pk == 1) {
    #pragma unroll
    for (int m = 0; m < 4; ++m)
      #pragma unroll
      for (int n = 0; n < 4; ++n)
        *(f32x4*)&ex[((m * 4 + n) * 1024 + st * 4)] = acc[m][n];
  }
  __syncthreads();
  if (pk == 0) {
    #pragma unroll
    for (int m = 0; m < 4; ++m)
      #pragma unroll
      for (int n = 0; n < 4; ++n) {
        f32x4 o = *(const f32x4*)&ex[((m * 4 + n) * 1024 + st * 4)];
        acc[m][n] += o;
      }
    const int crow0 = bm + wm * 64 + (lane >> 4) * 4;
    const int ccol0 = bn + wn * 64 + (lane & 15);
    const int seg = bn / 768;                   // block-constant (768%128==0)
    const int lcol0 = (bn % 768) + wn * 64 + (lane & 15);
    #pragma unroll
    for (int m = 0; m < 4; ++m) {
      #pragma unroll
      for (int n = 0; n < 4; ++n) {
        int col = ccol0 + n * 16;
        #pragma unroll
        for (int r = 0; r < 4; ++r) {
          int row = crow0 + m * 16 + r;
          float v = acc[m][n][r];
          if constexpr (EPI & 1) v += bias[col];
          if constexpr (EPI & 4) v += resid[(size_t)row * N + col];
          if constexpr (EPI & 2) v = fmaxf(v, 0.f);
          if constexpr (EPI & 8) Cf[(size_t)row * N + col] = v;
          if constexpr (EPI & 16) Cb[(size_t)row * N + col] = f2bf(v);
          if constexpr (EPI & 32)
            Cb[(size_t)seg * segN + (size_t)row * 768 + lcol0 + n * 16] = f2bf(v);
        }
      }
    }
  }
}

// ------------------------------------------------------------- attention ---
// Swapped-QK^T causal flash attention, paired q-blocks, static-max softmax,
// counted-vmcnt barriers (R9 version, unchanged).
__global__ void attn_fwd(const unsigned short* __restrict__ q,
                         const unsigned short* __restrict__ k,
                         const unsigned short* __restrict__ vT,
                         unsigned short* __restrict__ z) {
  __shared__ unsigned short Klds[2 * 2 * 64 * 32];
  __shared__ unsigned short Vlds[2 * 2 * 64 * 32];
  __shared__ unsigned short Plds[4 * 16 * 72];

  const int wgid = xcd_swz(blockIdx.x, gridDim.x);
  const int pi = wgid & 15;
  const int bh = wgid >> 4;
  const int b = bh / 12, h = bh % 12;
  const int tid = threadIdx.x, lane = tid & 63, w = tid >> 6;
  const int q16 = lane & 15;
  const int qt  = lane >> 4;
  const int rdc = ((qt ^ ((q16 >> 1) & 3)) * 8);

  const int srow = tid >> 2;
  const int sdc  = (tid & 3) * 8;
  const int sgc  = (((tid & 3) ^ ((srow >> 1) & 3)) * 8);
  const size_t kbase = (size_t)(b * 2048) * 768 + h * 64;
  const size_t vbase = (size_t)((b * 12 + h) * 64) * 2048;
  unsigned short* Pw = &Plds[w * 16 * 72];

  #pragma unroll 1
  for (int seg = 0; seg < 2; ++seg) {
    const int qb = seg == 0 ? pi : 31 - pi;
    const int q0 = qb * 64;
    const int nt = qb + 1;

    const int qrow = q0 + w * 16 + q16;
    const size_t qoff = (size_t)(b * 2048 + qrow) * 768 + h * 64 + qt * 8;
    bf16x8 qf0 = *(const bf16x8*)&q[qoff];
    bf16x8 qf1 = *(const bf16x8*)&q[qoff + 32];

    f32x4 accO[4] = {};
    float lrow = 0.f;

    #pragma unroll
    for (int i = 0; i < 2; ++i) {
      gload16(&k[kbase + (size_t)srow * 768 + i * 32 + sgc],
              &Klds[i * 2048 + srow * 32 + sdc]);
      gload16(&vT[vbase + (size_t)srow * 2048 + i * 32 + sgc],
              &Vlds[i * 2048 + srow * 32 + sdc]);
    }
    __syncthreads();     // full drain once per segment

    int buf = 0;
    for (int t = 0; t < nt; ++t) {
      if (t + 1 < nt) {
        const int kv1 = (t + 1) * 64;
        const int bo = (buf ^ 1) * 4096;
        #pragma unroll
        for (int i = 0; i < 2; ++i) {
          gload16(&k[kbase + (size_t)(kv1 + srow) * 768 + i * 32 + sgc],
                  &Klds[bo + i * 2048 + srow * 32 + sdc]);
          gload16(&vT[vbase + (size_t)srow * 2048 + kv1 + i * 32 + sgc],
                  &Vlds[bo + i * 2048 + srow * 32 + sdc]);
        }
        VMW4;            // waits only stage(t) (issued last iteration)
      } else {
        VMW0;
      }
      __builtin_amdgcn_s_barrier();   // stage(t) visible to all waves

      const int kv0 = t * 64;
      const int kb_ = buf * 4096;

      // S = K Q^T: 4 independent k0-MFMAs, then 4 k1-MFMAs
      bf16x8 kf0[4], kf1[4];
      #pragma unroll
      for (int n = 0; n < 4; ++n) {
        kf0[n] = *(const bf16x8*)&Klds[kb_ + 0 * 2048 + (n * 16 + q16) * 32 + rdc];
        kf1[n] = *(const bf16x8*)&Klds[kb_ + 1 * 2048 + (n * 16 + q16) * 32 + rdc];
      }
      f32x4 s[4];
      __builtin_amdgcn_s_setprio(1);
      #pragma unroll
      for (int n = 0; n < 4; ++n) {
        f32x4 zz = {};
        s[n] = __builtin_amdgcn_mfma_f32_16x16x32_bf16(kf0[n], qf0, zz, 0, 0, 0);
      }
      #pragma unroll
      for (int n = 0; n < 4; ++n)
        s[n] = __builtin_amdgcn_mfma_f32_16x16x32_bf16(kf1[n], qf1, s[n], 0, 0, 0);
      __builtin_amdgcn_s_setprio(0);

      if (t == nt - 1) {
        const int rowg = q0 + w * 16 + q16;
        #pragma unroll
        for (int n = 0; n < 4; ++n)
          #pragma unroll
          for (int r = 0; r < 4; ++r)
            if (kv0 + n * 16 + qt * 4 + r > rowg) s[n][r] = -3.0e38f;
      }

      // p = exp2(s); in-lane partial row-sum (cross-lane sum deferred)
      #pragma unroll
      for (int n = 0; n < 4; ++n)
        #pragma unroll
        for (int r = 0; r < 4; ++r) { s[n][r] = exp2f(s[n][r]); lrow += s[n][r]; }

      #pragma unroll
      for (int n = 0; n < 4; ++n) {
        unsigned int lo, hi;
        asm("v_cvt_pk_bf16_f32 %0, %1, %2" : "=v"(lo) : "v"(s[n][0]), "v"(s[n][1]));
        asm("v_cvt_pk_bf16_f32 %0, %1, %2" : "=v"(hi) : "v"(s[n][2]), "v"(s[n][3]));
        uint2 pk; pk.x = lo; pk.y = hi;
        *(uint2*)&Pw[q16 * 72 + n * 16 + qt * 4] = pk;
      }

      __builtin_amdgcn_s_setprio(1);
      #pragma unroll
      for (int kk = 0; kk < 2; ++kk) {
        bf16x8 pf = *(const bf16x8*)&Pw[q16 * 72 + kk * 32 + qt * 8];
        #pragma unroll
        for (int n = 0; n < 4; ++n) {
          bf16x8 vf = *(const bf16x8*)&Vlds[kb_ + kk * 2048 + (n * 16 + q16) * 32 + rdc];
          accO[n] = __builtin_amdgcn_mfma_f32_16x16x32_bf16(pf, vf, accO[n], 0, 0, 0);
        }
      }
      __builtin_amdgcn_s_setprio(0);

      __builtin_amdgcn_s_barrier();
      buf ^= 1;
    }

    // epilogue: complete the row sum across kv-quarter lanes, then divide
    lrow += __shfl_xor(lrow, 16);
    lrow += __shfl_xor(lrow, 32);
    #pragma unroll
    for (int r = 0; r < 4; ++r) {
      float lr = __int_as_float(__builtin_amdgcn_ds_bpermute((qt * 4 + r) * 4,
                                                             __float_as_int(lrow)));
      float linv = 1.0f / lr;
      int rowg = q0 + w * 16 + qt * 4 + r;
      #pragma unroll
      for (int n = 0; n < 4; ++n)
        z[(size_t)(b * 2048 + rowg) * 768 + h * 64 + n * 16 + q16]
            = f2bf(accO[n][r] * linv);
    }
  }
}

// ---------------------------------------------------------------- launch ---
extern "C" void kernel_launch(void* const* d_in, const int* in_sizes, int n_in,
                              void* d_out, int out_size, void* d_ws, size_t ws_size,
                              hipStream_t stream) {
  const float* x  = (const float*)d_in[0];
  const float* Wq = (const float*)d_in[1];
  const float* Wk = (const float*)d_in[2];
  const float* Wv = (const float*)d_in[3];
  const float* Wo = (const float*)d_in[4];
  const float* bo = (const float*)d_in[5];
  const float* W1 = (const float*)d_in[6];
  const float* b1 = (const float*)d_in[7];
  const float* W2 = (const float*)d_in[8];
  const float* b2 = (const float*)d_in[9];
  float* out = (float*)d_out;

  const int B = 4, S = 2048, D = 768, H = 12, hs = 64, F = 3072;
  const int M = B * S;                 // 8192
  const size_t MD = (size_t)M * D;     // 6291456

  unsigned short* xb   = (unsigned short*)d_ws;
  unsigned short* qb   = xb + MD;
  unsigned short* kb   = qb + MD;
  unsigned short* vb   = kb + MD;
  unsigned short* hbuf = xb;           // [M, F] bf16, reuse
  unsigned short* vT   = vb + MD;
  unsigned short* zb   = vT + MD;
  float*          z2f  = (float*)(zb + MD);
  unsigned short* z2b  = (unsigned short*)(z2f + MD);
  unsigned short* wqkvT= z2b + MD;     // [2304][768] bf16
  unsigned short* woT  = wqkvT + 3 * (size_t)D * D;
  unsigned short* w1T  = woT + (size_t)D * D;
  unsigned short* w2T  = w1T + (size_t)D * F;

  // q scale folds 1/sqrt(64) AND log2(e): softmax runs in exp2 domain
  const float QS = 0.125f * 1.4426950408889634f;

  // fused prep: castx + Wq/Wk/Wv transpose + Wo/W1/W2 transpose
  prep<<<dim3(13056), 256, 0, stream>>>(x, xb, Wq, Wk, Wv, wqkvT,
                                        Wo, W1, W2, woT, w1T, w2T, QS);

  // fused QKV: [M,768] @ [768,2304] -> q,k,v bf16 (split store), split-K
  {
    int gy = 3 * D / 128;  // 18
    gemm_skb<32><<<dim3(64 * gy), 512, 0, stream>>>(
        xb, wqkvT, nullptr, nullptr, nullptr, qb, M, 3 * D, D, gy, MD);
  }

  vtrans<<<dim3(S / 32, hs / 32, B * H), dim3(32, 8), 0, stream>>>(vb, vT);

  attn_fwd<<<dim3((S / 128) * B * H), 256, 0, stream>>>(qb, kb, vT, zb);

  // z @ Wo + bo + x -> z2 (fp32 + bf16), in-block split-K
  {
    int gy = D / 128;  // 6
    gemm_skb<1 | 4 | 8 | 16><<<dim3(64 * gy), 512, 0, stream>>>(
        zb, woT, bo, x, z2f, z2b, M, D, D, gy, 0);
  }
  // relu(z2 @ W1 + b1) -> h (bf16), in-block split-K
  {
    int gy = F / 128;  // 24
    gemm_skb<1 | 2 | 16><<<dim3(64 * gy), 512, 0, stream>>>(
        z2b, w1T, b1, nullptr, nullptr, hbuf, M, F, D, gy, 0);
  }
  // h @ W2 + b2 + z2 -> out (fp32), in-block split-K
  {
    int gy = D / 128;  // 6
    gemm_skb<1 | 4 | 8><<<dim3(64 * gy), 512, 0, stream>>>(
        hbuf, w2T, b2, z2f, out, nullptr, M, D, F, gy, 0);
  }
}

// Round 21
// 258.324 us; speedup vs baseline: 1.0260x; 1.0260x over previous
//
#include <hip/hip_runtime.h>

// ---------------------------------------------------------------------------
// TransformerBlock on MI355X (gfx950): bf16 MFMA pipeline
//   B=4 S=2048 D=768 H=12 hs=64 F=3072, M=B*S=8192
// Round 21: FINAL = R19 configuration restored (best: 258.4 us).
//   prep (castx+transposes) | QKV on gemm_skb (split-K, split-store) |
//   vtrans | attn (swapped-QK^T, static-max, counted-vmcnt) |
//   Wo on gemm_skb | W1 on gemm_big (256x128) | W2 on gemm_skb.
//   R20's W1-on-skb regressed (+6.6 us) and is reverted.
// ---------------------------------------------------------------------------

typedef __attribute__((ext_vector_type(4))) float f32x4;
typedef __attribute__((ext_vector_type(8))) short bf16x8;   // 8 bf16 in 4 VGPRs
typedef __attribute__((ext_vector_type(4))) unsigned short u16x4;

#define GLB_AS __attribute__((address_space(1)))
#define LDS_AS __attribute__((address_space(3)))

__device__ __forceinline__ unsigned short f2bf(float f) {
  unsigned int u = __float_as_uint(f);
  u = (u + 0x7FFFu + ((u >> 16) & 1u)) >> 16;   // RNE
  return (unsigned short)u;
}

__device__ __forceinline__ void gload16(const void* g, void* l) {
  __builtin_amdgcn_global_load_lds((const GLB_AS unsigned int*)g,
                                   (LDS_AS unsigned int*)l, 16, 0, 0);
}

// bijective XCD swizzle (m204): contiguous chunk of wg-ids per XCD
__device__ __forceinline__ int xcd_swz(int orig, int nwg) {
  int q = nwg >> 3, r = nwg & 7;
  int xcd = orig & 7, rest = orig >> 3;
  return (xcd < r ? xcd * (q + 1) : r * (q + 1) + (xcd - r) * q) + rest;
}

#define VMW4 asm volatile("s_waitcnt vmcnt(4)" ::: "memory")
#define VMW3 asm volatile("s_waitcnt vmcnt(3)" ::: "memory")
#define VMW0 asm volatile("s_waitcnt vmcnt(0)" ::: "memory")

// ----------------------------------------------- fused prep (one launch) ---
// blocks [0,6144): castx | [6144,7872): Wq/Wk/Wv transpose | [7872,13056): W
__global__ void prep(const float* __restrict__ x, unsigned short* __restrict__ xb,
                     const float* __restrict__ Wq, const float* __restrict__ Wk,
                     const float* __restrict__ Wv, unsigned short* __restrict__ wqkvT,
                     const float* __restrict__ Wo, const float* __restrict__ W1,
                     const float* __restrict__ W2, unsigned short* __restrict__ woT,
                     unsigned short* __restrict__ w1T, unsigned short* __restrict__ w2T,
                     float qscale) {
  __shared__ float tile[32][33];
  const int id = blockIdx.x;
  const int tid = threadIdx.x;

  if (id < 6144) {                       // ---- castx: 6144*256*4 = 6291456
    int i = (id * 256 + tid) * 4;
    float4 f = *(const float4*)&x[i];
    u16x4 o;
    o[0] = f2bf(f.x); o[1] = f2bf(f.y); o[2] = f2bf(f.z); o[3] = f2bf(f.w);
    *(u16x4*)&xb[i] = o;
    return;
  }

  const int tx = tid & 31, ty = tid >> 5;     // (32,8) mapping
  const float* in; unsigned short* out; int C, R, bx, by; float scale = 1.0f;

  if (id < 7872) {                       // ---- tcast3: Wq/Wk/Wv [768x64] x36
    int id2 = id - 6144;                 // [0,1728)
    int z = id2 / 48, rem = id2 % 48;
    int wsel = z / 12, head = z % 12;
    R = 768; C = 64;
    in = (wsel == 0 ? Wq : wsel == 1 ? Wk : Wv) + (size_t)head * R * C;
    out = wqkvT + (size_t)wsel * R * R + (size_t)head * R * C;
    if (wsel == 0) scale = qscale;
    bx = (rem & 1) * 32; by = (rem >> 1) * 32;
  } else {                               // ---- tcastW: Wo/W1/W2
    int id3 = id - 7872;                 // [0,5184)
    int gx;
    if (id3 < 576)       {             in = Wo; out = woT; C = 768;  gx = 24; R = 768; }
    else if (id3 < 2880) { id3 -= 576;  in = W1; out = w1T; C = 3072; gx = 96; R = 768; }
    else                 { id3 -= 2880; in = W2; out = w2T; C = 768;  gx = 24; R = 3072; }
    bx = (id3 % gx) * 32; by = (id3 / gx) * 32;
  }

  #pragma unroll
  for (int i = 0; i < 32; i += 8)
    tile[ty + i][tx] = in[(size_t)(by + ty + i) * C + bx + tx];
  __syncthreads();
  #pragma unroll
  for (int i = 0; i < 32; i += 8)
    out[(size_t)(bx + ty + i) * R + by + tx] = f2bf(tile[tx][ty + i] * scale);
}

// ------------------------------------------------- v -> vT (bf16->bf16) ----
__global__ void vtrans(const unsigned short* __restrict__ v, unsigned short* __restrict__ vT) {
  __shared__ unsigned short tile[32][33];
  int bh = blockIdx.z, b = bh / 12, h = bh % 12;
  int s0 = blockIdx.x * 32, e0 = blockIdx.y * 32;
  int tx = threadIdx.x, ty = threadIdx.y;
  #pragma unroll
  for (int i = 0; i < 32; i += 8)
    tile[ty + i][tx] = v[(size_t)(b * 2048 + s0 + ty + i) * 768 + h * 64 + e0 + tx];
  __syncthreads();
  #pragma unroll
  for (int i = 0; i < 32; i += 8)
    vT[(size_t)((b * 12 + h) * 64 + e0 + ty + i) * 2048 + s0 + tx] = tile[tx][ty + i];
}

// --------------------------------------- GEMM 128x128, in-block split-K ---
// (QKV / Wo / W2) 8 waves = 2 pipelines x 4 waves; pipeline p covers K-half
// p in its own 32KB LDS double-buffer (64KB total, 2 blocks/CU).
// Combine: pipeline1 acc -> LDS, __syncthreads, pipeline0 adds + epilogue.
// EPI bits: 1 bias, 4 resid(fp32), 8 fp32 store, 16 bf16 store,
//           32 QKV split bf16 store (row stride 768, seg stride segN).
template <int EPI>
__global__ __launch_bounds__(512, 2)
void gemm_skb(const unsigned short* __restrict__ A,
              const unsigned short* __restrict__ Bt,
              const float* __restrict__ bias,
              const float* __restrict__ resid,
              float* __restrict__ Cf,
              unsigned short* __restrict__ Cb,
              int M, int N, int K, int gy, size_t segN) {
  __shared__ unsigned short SH[32768];          // 64 KB
  const int tid = threadIdx.x;
  const int lane = tid & 63;
  const int w = tid >> 6;
  const int pk = w >> 2;                        // pipeline 0/1
  const int wl = w & 3;
  const int wm = wl & 1, wn = wl >> 1;

  const int wg = xcd_swz(blockIdx.x, gridDim.x);
  const int gsz = 8 * gy;
  const int group = wg / gsz;
  const int rem = wg - group * gsz;
  const int bm = (group * 8 + (rem & 7)) * 128;
  const int bn = (rem >> 3) * 128;

  const int Kh = K >> 1;
  const int kof = pk * Kh;
  unsigned short* Abase = SH + pk * 8192;           // [buf][128*32]
  unsigned short* Bbase = SH + 16384 + pk * 8192;

  f32x4 acc[4][4] = {};

  const int st = tid & 255;                     // per-pipeline staging id
  const int r0 = st >> 2;
  const int c0 = (st & 3) * 8;

  // prologue: stage K-half tile 0 into buf 0 (each pipeline its own)
  #pragma unroll
  for (int i = 0; i < 2; ++i) {
    int row = r0 + i * 64;
    gload16(&A[(size_t)(bm + row) * K + kof + c0], &Abase[row * 32 + c0]);
    gload16(&Bt[(size_t)(bn + row) * K + kof + c0], &Bbase[row * 32 + c0]);
  }
  __syncthreads();

  int buf = 0;
  for (int k0 = 0; k0 < Kh; k0 += 32) {
    if (k0 + 32 < Kh) {
      #pragma unroll
      for (int i = 0; i < 2; ++i) {
        int row = r0 + i * 64;
        gload16(&A[(size_t)(bm + row) * K + kof + k0 + 32 + c0],
                &Abase[(buf ^ 1) * 4096 + row * 32 + c0]);
        gload16(&Bt[(size_t)(bn + row) * K + kof + k0 + 32 + c0],
                &Bbase[(buf ^ 1) * 4096 + row * 32 + c0]);
      }
      VMW4;
    } else {
      VMW0;
    }
    __builtin_amdgcn_s_barrier();

    bf16x8 af[4], bf[4];
    #pragma unroll
    for (int m = 0; m < 4; ++m)
      af[m] = *(const bf16x8*)&Abase[buf * 4096 + (wm * 64 + m * 16 + (lane & 15)) * 32 + (lane >> 4) * 8];
    #pragma unroll
    for (int n = 0; n < 4; ++n)
      bf[n] = *(const bf16x8*)&Bbase[buf * 4096 + (wn * 64 + n * 16 + (lane & 15)) * 32 + (lane >> 4) * 8];
    #pragma unroll
    for (int m = 0; m < 4; ++m)
      #pragma unroll
      for (int n = 0; n < 4; ++n)
        acc[m][n] = __builtin_amdgcn_mfma_f32_16x16x32_bf16(af[m], bf[n], acc[m][n], 0, 0, 0);

    __builtin_amdgcn_s_barrier();
    buf ^= 1;
  }

  // combine the two K-half partials via LDS (full compiler fence both sides)
  __syncthreads();
  float* ex = (float*)SH;                       // 16384 floats = 64 KB
  if (pk == 1) {
    #pragma unroll
    for (int m = 0; m < 4; ++m)
      #pragma unroll
      for (int n = 0; n < 4; ++n)
        *(f32x4*)&ex[((m * 4 + n) * 1024 + st * 4)] = acc[m][n];
  }
  __syncthreads();
  if (pk == 0) {
    #pragma unroll
    for (int m = 0; m < 4; ++m)
      #pragma unroll
      for (int n = 0; n < 4; ++n) {
        f32x4 o = *(const f32x4*)&ex[((m * 4 + n) * 1024 + st * 4)];
        acc[m][n] += o;
      }
    const int crow0 = bm + wm * 64 + (lane >> 4) * 4;
    const int ccol0 = bn + wn * 64 + (lane & 15);
    const int seg = bn / 768;                   // block-constant (768%128==0)
    const int lcol0 = (bn % 768) + wn * 64 + (lane & 15);
    #pragma unroll
    for (int m = 0; m < 4; ++m) {
      #pragma unroll
      for (int n = 0; n < 4; ++n) {
        int col = ccol0 + n * 16;
        #pragma unroll
        for (int r = 0; r < 4; ++r) {
          int row = crow0 + m * 16 + r;
          float v = acc[m][n][r];
          if constexpr (EPI & 1) v += bias[col];
          if constexpr (EPI & 4) v += resid[(size_t)row * N + col];
          if constexpr (EPI & 8) Cf[(size_t)row * N + col] = v;
          if constexpr (EPI & 16) Cb[(size_t)row * N + col] = f2bf(v);
          if constexpr (EPI & 32)
            Cb[(size_t)seg * segN + (size_t)row * 768 + lcol0 + n * 16] = f2bf(v);
        }
      }
    }
  }
}

// --------------------------------------------------------- GEMM 256x128 ---
// (W1) 8 waves (4m x 2n), BK=32, 48 KB LDS dbuf, vmcnt(3) ledger.
// EPI bits: 1 bias, 2 relu, 16 bf16 store.
#define BSTG(bb, kt) {                                                     \
    _Pragma("unroll") for (int i = 0; i < 2; ++i) {                        \
      int ch = tid + 512 * i;                                              \
      gload16(&A[(size_t)(bm + (ch >> 2)) * K + (kt) + (ch & 3) * 8],      \
              &Alds[bb][(ch >> 2) * 32 + (ch & 3) * 8]);                   \
    }                                                                      \
    gload16(&Bt[(size_t)(bn + (tid >> 2)) * K + (kt) + (tid & 3) * 8],     \
            &Blds[bb][(tid >> 2) * 32 + (tid & 3) * 8]); }

template <int EPI>
__global__ __launch_bounds__(512, 2)
void gemm_big(const unsigned short* __restrict__ A,
              const unsigned short* __restrict__ Bt,
              const float* __restrict__ bias,
              unsigned short* __restrict__ Cb,
              int M, int N, int K, int gy, size_t segN) {
  __shared__ unsigned short Alds[2][256 * 32];
  __shared__ unsigned short Blds[2][128 * 32];
  const int tid = threadIdx.x;
  const int lane = tid & 63;
  const int w = tid >> 6;
  const int wr = w >> 1, wc = w & 1;            // 4 x 2 wave grid (64x64 each)
  const int q16 = lane & 15, qt = lane >> 4;

  const int wg = xcd_swz(blockIdx.x, gridDim.x);
  const int gsz = 8 * gy;
  const int group = wg / gsz;
  const int rem = wg - group * gsz;
  const int bm = (group * 8 + (rem & 7)) * 256;
  const int bn = (rem >> 3) * 128;

  f32x4 acc[4][4] = {};

  BSTG(0, 0);
  __syncthreads();

  int buf = 0;
  for (int k0 = 0; k0 < K; k0 += 32) {
    if (k0 + 32 < K) {
      BSTG(buf ^ 1, k0 + 32);
      VMW3;
    } else {
      VMW0;
    }
    __builtin_amdgcn_s_barrier();

    bf16x8 af[4], bf[4];
    #pragma unroll
    for (int m = 0; m < 4; ++m)
      af[m] = *(const bf16x8*)&Alds[buf][(wr * 64 + m * 16 + q16) * 32 + qt * 8];
    #pragma unroll
    for (int n = 0; n < 4; ++n)
      bf[n] = *(const bf16x8*)&Blds[buf][(wc * 64 + n * 16 + q16) * 32 + qt * 8];
    #pragma unroll
    for (int m = 0; m < 4; ++m)
      #pragma unroll
      for (int n = 0; n < 4; ++n)
        acc[m][n] = __builtin_amdgcn_mfma_f32_16x16x32_bf16(af[m], bf[n], acc[m][n], 0, 0, 0);

    __builtin_amdgcn_s_barrier();
    buf ^= 1;
  }

  const int crow0 = bm + wr * 64 + qt * 4;
  const int ccol0 = bn + wc * 64 + q16;
  const int seg = bn / 768;
  const int lcol0 = (bn % 768) + wc * 64 + q16;
  #pragma unroll
  for (int m = 0; m < 4; ++m) {
    #pragma unroll
    for (int n = 0; n < 4; ++n) {
      int col = ccol0 + n * 16;
      #pragma unroll
      for (int r = 0; r < 4; ++r) {
        int row = crow0 + m * 16 + r;
        float v = acc[m][n][r];
        if constexpr (EPI & 1) v += bias[col];
        if constexpr (EPI & 2) v = fmaxf(v, 0.f);
        if constexpr (EPI & 16) Cb[(size_t)row * N + col] = f2bf(v);
        if constexpr (EPI & 32)
          Cb[(size_t)seg * segN + (size_t)row * 768 + lcol0 + n * 16] = f2bf(v);
      }
    }
  }
}

// ------------------------------------------------------------- attention ---
// Swapped-QK^T causal flash attention, paired q-blocks, static-max softmax,
// counted-vmcnt barriers (R9 version, unchanged).
__global__ void attn_fwd(const unsigned short* __restrict__ q,
                         const unsigned short* __restrict__ k,
                         const unsigned short* __restrict__ vT,
                         unsigned short* __restrict__ z) {
  __shared__ unsigned short Klds[2 * 2 * 64 * 32];
  __shared__ unsigned short Vlds[2 * 2 * 64 * 32];
  __shared__ unsigned short Plds[4 * 16 * 72];

  const int wgid = xcd_swz(blockIdx.x, gridDim.x);
  const int pi = wgid & 15;
  const int bh = wgid >> 4;
  const int b = bh / 12, h = bh % 12;
  const int tid = threadIdx.x, lane = tid & 63, w = tid >> 6;
  const int q16 = lane & 15;
  const int qt  = lane >> 4;
  const int rdc = ((qt ^ ((q16 >> 1) & 3)) * 8);

  const int srow = tid >> 2;
  const int sdc  = (tid & 3) * 8;
  const int sgc  = (((tid & 3) ^ ((srow >> 1) & 3)) * 8);
  const size_t kbase = (size_t)(b * 2048) * 768 + h * 64;
  const size_t vbase = (size_t)((b * 12 + h) * 64) * 2048;
  unsigned short* Pw = &Plds[w * 16 * 72];

  #pragma unroll 1
  for (int seg = 0; seg < 2; ++seg) {
    const int qb = seg == 0 ? pi : 31 - pi;
    const int q0 = qb * 64;
    const int nt = qb + 1;

    const int qrow = q0 + w * 16 + q16;
    const size_t qoff = (size_t)(b * 2048 + qrow) * 768 + h * 64 + qt * 8;
    bf16x8 qf0 = *(const bf16x8*)&q[qoff];
    bf16x8 qf1 = *(const bf16x8*)&q[qoff + 32];

    f32x4 accO[4] = {};
    float lrow = 0.f;

    #pragma unroll
    for (int i = 0; i < 2; ++i) {
      gload16(&k[kbase + (size_t)srow * 768 + i * 32 + sgc],
              &Klds[i * 2048 + srow * 32 + sdc]);
      gload16(&vT[vbase + (size_t)srow * 2048 + i * 32 + sgc],
              &Vlds[i * 2048 + srow * 32 + sdc]);
    }
    __syncthreads();     // full drain once per segment

    int buf = 0;
    for (int t = 0; t < nt; ++t) {
      if (t + 1 < nt) {
        const int kv1 = (t + 1) * 64;
        const int bo = (buf ^ 1) * 4096;
        #pragma unroll
        for (int i = 0; i < 2; ++i) {
          gload16(&k[kbase + (size_t)(kv1 + srow) * 768 + i * 32 + sgc],
                  &Klds[bo + i * 2048 + srow * 32 + sdc]);
          gload16(&vT[vbase + (size_t)srow * 2048 + kv1 + i * 32 + sgc],
                  &Vlds[bo + i * 2048 + srow * 32 + sdc]);
        }
        VMW4;            // waits only stage(t) (issued last iteration)
      } else {
        VMW0;
      }
      __builtin_amdgcn_s_barrier();   // stage(t) visible to all waves

      const int kv0 = t * 64;
      const int kb_ = buf * 4096;

      // S = K Q^T: 4 independent k0-MFMAs, then 4 k1-MFMAs
      bf16x8 kf0[4], kf1[4];
      #pragma unroll
      for (int n = 0; n < 4; ++n) {
        kf0[n] = *(const bf16x8*)&Klds[kb_ + 0 * 2048 + (n * 16 + q16) * 32 + rdc];
        kf1[n] = *(const bf16x8*)&Klds[kb_ + 1 * 2048 + (n * 16 + q16) * 32 + rdc];
      }
      f32x4 s[4];
      __builtin_amdgcn_s_setprio(1);
      #pragma unroll
      for (int n = 0; n < 4; ++n) {
        f32x4 zz = {};
        s[n] = __builtin_amdgcn_mfma_f32_16x16x32_bf16(kf0[n], qf0, zz, 0, 0, 0);
      }
      #pragma unroll
      for (int n = 0; n < 4; ++n)
        s[n] = __builtin_amdgcn_mfma_f32_16x16x32_bf16(kf1[n], qf1, s[n], 0, 0, 0);
      __builtin_amdgcn_s_setprio(0);

      if (t == nt - 1) {
        const int rowg = q0 + w * 16 + q16;
        #pragma unroll
        for (int n = 0; n < 4; ++n)
          #pragma unroll
          for (int r = 0; r < 4; ++r)
            if (kv0 + n * 16 + qt * 4 + r > rowg) s[n][r] = -3.0e38f;
      }

      // p = exp2(s); in-lane partial row-sum (cross-lane sum deferred)
      #pragma unroll
      for (int n = 0; n < 4; ++n)
        #pragma unroll
        for (int r = 0; r < 4; ++r) { s[n][r] = exp2f(s[n][r]); lrow += s[n][r]; }

      #pragma unroll
      for (int n = 0; n < 4; ++n) {
        unsigned int lo, hi;
        asm("v_cvt_pk_bf16_f32 %0, %1, %2" : "=v"(lo) : "v"(s[n][0]), "v"(s[n][1]));
        asm("v_cvt_pk_bf16_f32 %0, %1, %2" : "=v"(hi) : "v"(s[n][2]), "v"(s[n][3]));
        uint2 pk; pk.x = lo; pk.y = hi;
        *(uint2*)&Pw[q16 * 72 + n * 16 + qt * 4] = pk;
      }

      __builtin_amdgcn_s_setprio(1);
      #pragma unroll
      for (int kk = 0; kk < 2; ++kk) {
        bf16x8 pf = *(const bf16x8*)&Pw[q16 * 72 + kk * 32 + qt * 8];
        #pragma unroll
        for (int n = 0; n < 4; ++n) {
          bf16x8 vf = *(const bf16x8*)&Vlds[kb_ + kk * 2048 + (n * 16 + q16) * 32 + rdc];
          accO[n] = __builtin_amdgcn_mfma_f32_16x16x32_bf16(pf, vf, accO[n], 0, 0, 0);
        }
      }
      __builtin_amdgcn_s_setprio(0);

      __builtin_amdgcn_s_barrier();
      buf ^= 1;
    }

    // epilogue: complete the row sum across kv-quarter lanes, then divide
    lrow += __shfl_xor(lrow, 16);
    lrow += __shfl_xor(lrow, 32);
    #pragma unroll
    for (int r = 0; r < 4; ++r) {
      float lr = __int_as_float(__builtin_amdgcn_ds_bpermute((qt * 4 + r) * 4,
                                                             __float_as_int(lrow)));
      float linv = 1.0f / lr;
      int rowg = q0 + w * 16 + qt * 4 + r;
      #pragma unroll
      for (int n = 0; n < 4; ++n)
        z[(size_t)(b * 2048 + rowg) * 768 + h * 64 + n * 16 + q16]
            = f2bf(accO[n][r] * linv);
    }
  }
}

// ---------------------------------------------------------------- launch ---
extern "C" void kernel_launch(void* const* d_in, const int* in_sizes, int n_in,
                              void* d_out, int out_size, void* d_ws, size_t ws_size,
                              hipStream_t stream) {
  const float* x  = (const float*)d_in[0];
  const float* Wq = (const float*)d_in[1];
  const float* Wk = (const float*)d_in[2];
  const float* Wv = (const float*)d_in[3];
  const float* Wo = (const float*)d_in[4];
  const float* bo = (const float*)d_in[5];
  const float* W1 = (const float*)d_in[6];
  const float* b1 = (const float*)d_in[7];
  const float* W2 = (const float*)d_in[8];
  const float* b2 = (const float*)d_in[9];
  float* out = (float*)d_out;

  const int B = 4, S = 2048, D = 768, H = 12, hs = 64, F = 3072;
  const int M = B * S;                 // 8192
  const size_t MD = (size_t)M * D;     // 6291456

  unsigned short* xb   = (unsigned short*)d_ws;
  unsigned short* qb   = xb + MD;
  unsigned short* kb   = qb + MD;
  unsigned short* vb   = kb + MD;
  unsigned short* hbuf = xb;           // [M, F] bf16, reuse
  unsigned short* vT   = vb + MD;
  unsigned short* zb   = vT + MD;
  float*          z2f  = (float*)(zb + MD);
  unsigned short* z2b  = (unsigned short*)(z2f + MD);
  unsigned short* wqkvT= z2b + MD;     // [2304][768] bf16
  unsigned short* woT  = wqkvT + 3 * (size_t)D * D;
  unsigned short* w1T  = woT + (size_t)D * D;
  unsigned short* w2T  = w1T + (size_t)D * F;

  // q scale folds 1/sqrt(64) AND log2(e): softmax runs in exp2 domain
  const float QS = 0.125f * 1.4426950408889634f;

  // fused prep: castx + Wq/Wk/Wv transpose + Wo/W1/W2 transpose
  prep<<<dim3(13056), 256, 0, stream>>>(x, xb, Wq, Wk, Wv, wqkvT,
                                        Wo, W1, W2, woT, w1T, w2T, QS);

  // fused QKV: [M,768] @ [768,2304] -> q,k,v bf16 (split store), split-K
  {
    int gy = 3 * D / 128;  // 18
    gemm_skb<32><<<dim3(64 * gy), 512, 0, stream>>>(
        xb, wqkvT, nullptr, nullptr, nullptr, qb, M, 3 * D, D, gy, MD);
  }

  vtrans<<<dim3(S / 32, hs / 32, B * H), dim3(32, 8), 0, stream>>>(vb, vT);

  attn_fwd<<<dim3((S / 128) * B * H), 256, 0, stream>>>(qb, kb, vT, zb);

  // z @ Wo + bo + x -> z2 (fp32 + bf16), in-block split-K
  {
    int gy = D / 128;  // 6
    gemm_skb<1 | 4 | 8 | 16><<<dim3(64 * gy), 512, 0, stream>>>(
        zb, woT, bo, x, z2f, z2b, M, D, D, gy, 0);
  }
  // relu(z2 @ W1 + b1) -> h (bf16), 256x128: 768 blocks = 3/CU
  {
    int gy = F / 128;  // 24
    gemm_big<1 | 2 | 16><<<dim3(32 * gy), 512, 0, stream>>>(z2b, w1T, b1, hbuf,
                                                            M, F, D, gy, 0);
  }
  // h @ W2 + b2 + z2 -> out (fp32), in-block split-K
  {
    int gy = D / 128;  // 6
    gemm_skb<1 | 4 | 8><<<dim3(64 * gy), 512, 0, stream>>>(
        hbuf, w2T, b2, z2f, out, nullptr, M, D, F, gy, 0);
  }
}